// Round 4
// baseline (315.475 us; speedup 1.0000x reference)
//
#include <hip/hip_runtime.h>
#include <stdint.h>

typedef unsigned short u16;
typedef float f32x16 __attribute__((ext_vector_type(16)));
typedef __bf16 bf16x8 __attribute__((ext_vector_type(8)));

#define B_ 4096
#define D_ 2048
#define U_ 2048
#define K_ 4096   // D + U
#define N_ 8192   // 4*U
#define NIT 32    // K / (2*64): 2 K-tiles (BK=64) per iteration

__device__ __forceinline__ u16 f32_bf16(float f) {
  uint32_t u = __float_as_uint(f);
  u += 0x7FFFu + ((u >> 16) & 1u);
  return (u16)(u >> 16);
}
__device__ __forceinline__ float hsig(float x) {
  return fminf(fmaxf(0.2f * x + 0.5f, 0.0f), 1.0f);
}
__device__ __forceinline__ float ftanh(float x) {
  x = fminf(fmaxf(x, -15.0f), 15.0f);
  float e = __expf(2.0f * x);
  return (e - 1.0f) / (e + 1.0f);
}
__device__ __forceinline__ void gload16(const void* g, void* l) {
  __builtin_amdgcn_global_load_lds(
      (const __attribute__((address_space(1))) void*)g,
      (__attribute__((address_space(3))) void*)l,
      16, 0, 0);
}

// ---- cast A = [inputs | h_tm1] -> bf16 [4096][4096] ----
__global__ __launch_bounds__(256) void cast_a(const float* __restrict__ x,
                                              const float* __restrict__ h,
                                              u16* __restrict__ A) {
  int c = blockIdx.x * 256 + threadIdx.x;
  int m = c >> 9;
  int kc = (c & 511) << 3;
  const float* src = (kc < D_) ? (x + (size_t)m * D_ + kc)
                               : (h + (size_t)m * U_ + (kc - D_));
  float4 v0 = ((const float4*)src)[0];
  float4 v1 = ((const float4*)src)[1];
  u16 o[8] = { f32_bf16(v0.x), f32_bf16(v0.y), f32_bf16(v0.z), f32_bf16(v0.w),
               f32_bf16(v1.x), f32_bf16(v1.y), f32_bf16(v1.z), f32_bf16(v1.w) };
  *(uint4*)(A + (size_t)c * 8) = *(const uint4*)o;
}

// ---- cast + transpose + gate-interleave W -> Wt[n'][k] bf16 [8192][4096] ----
// n' = ublk*128 + g*32 + ul  where u = ublk*32 + ul, original col n = g*2048 + u
__global__ __launch_bounds__(256) void cast_wt(const float* __restrict__ kern,
                                               const float* __restrict__ rker,
                                               u16* __restrict__ Wt) {
  __shared__ u16 sW[64][134];    // 67-dword stride (odd) -> no write conflicts
  const int t = threadIdx.x;
  const int bx = blockIdx.x;     // ublk 0..63
  const int by = blockIdx.y;     // k-block 0..63
  const int k0 = by * 64;
  const float* src = (k0 < D_) ? kern : rker;
  const int krow0 = (k0 < D_) ? k0 : (k0 - D_);
#pragma unroll
  for (int i = 0; i < 8; ++i) {
    int q  = i * 256 + t;        // float4 task 0..2047
    int kl = q >> 5;             // 0..63 local k row
    int cc = q & 31;             // float4 index within 128 n'-cols
    int g  = cc >> 3;
    int n  = g * U_ + bx * 32 + (cc & 7) * 4;
    float4 v = *(const float4*)(src + (size_t)(krow0 + kl) * N_ + n);
    u16 p[4] = { f32_bf16(v.x), f32_bf16(v.y), f32_bf16(v.z), f32_bf16(v.w) };
    *(ushort4*)&sW[kl][cc * 4] = *(const ushort4*)p;
  }
  __syncthreads();
#pragma unroll
  for (int j = 0; j < 4; ++j) {
    int c2 = j * 256 + t;        // task 0..1023
    int r  = c2 >> 3;            // 0..127 local n'
    int kc = c2 & 7;             // 8-elem chunk along k
    u16 p[8];
#pragma unroll
    for (int jj = 0; jj < 8; ++jj) p[jj] = sW[kc * 8 + jj][r];
    *(uint4*)(Wt + ((size_t)bx * 128 + r) * K_ + k0 + kc * 8) = *(const uint4*)p;
  }
}

// ======== 256x256 8-phase GEMM (32x32x16 MFMA, 1 barrier/phase) ========
// LDS: [parity][A=0/B=1][khalf][256 rows][32 elems]; 128 KiB.
// Row = 64B = 4 x 16B chunks; phys_chunk = logical ^ ((row>>1)&3).
#define ABASE(par, kk) ((par) * 65536 + (kk) * 16384)
#define BBASE(par, kk) ((par) * 65536 + 32768 + (kk) * 16384)

#define STAGE_A(par, kk, t) do { \
  const u16* gp_ = Ab + (size_t)grow * K_ + (t) * 64 + (kk) * 32 + gch8; \
  char* lp_ = ldsc + ABASE(par, kk) + wid * 1024; \
  gload16(gp_, lp_); \
  gload16(gp_ + (size_t)128 * K_, lp_ + 8192); \
} while (0)

#define STAGE_B(par, kk, t) do { \
  const u16* gp_ = Bb + (size_t)grow * K_ + (t) * 64 + (kk) * 32 + gch8; \
  char* lp_ = ldsc + BBASE(par, kk) + wid * 1024; \
  gload16(gp_, lp_); \
  gload16(gp_ + (size_t)128 * K_, lp_ + 8192); \
} while (0)

#define VMW(n) asm volatile("s_waitcnt vmcnt(" #n ")" ::: "memory")
#define MFMA32 __builtin_amdgcn_mfma_f32_32x32x16_bf16

// One phase: 6 ds_read_b128 + 1 stage + (optional vmcnt) + barrier + 8 MFMA.
#define PHASE(par, kk, ks, STAGE_STMT, VMW_STMT) do { \
  const char* pa_ = ldsc + ABASE(par, kk) + aob; \
  const char* pb_ = ldsc + BBASE(par, kk) + bob; \
  const int ck_ = (ks) ? ck1 : ck0; \
  bf16x8 av0 = *(const bf16x8*)(pa_ + ck_); \
  bf16x8 av1 = *(const bf16x8*)(pa_ + 2048 + ck_); \
  bf16x8 bv0 = *(const bf16x8*)(pb_ + ck_); \
  bf16x8 bv1 = *(const bf16x8*)(pb_ + 2048 + ck_); \
  bf16x8 bv2 = *(const bf16x8*)(pb_ + 4096 + ck_); \
  bf16x8 bv3 = *(const bf16x8*)(pb_ + 6144 + ck_); \
  STAGE_STMT; \
  VMW_STMT; \
  __builtin_amdgcn_s_barrier(); \
  asm volatile("s_waitcnt lgkmcnt(0)" ::: "memory"); \
  __builtin_amdgcn_s_setprio(1); \
  acc[0][0] = MFMA32(av0, bv0, acc[0][0], 0, 0, 0); \
  acc[0][1] = MFMA32(av0, bv1, acc[0][1], 0, 0, 0); \
  acc[0][2] = MFMA32(av0, bv2, acc[0][2], 0, 0, 0); \
  acc[0][3] = MFMA32(av0, bv3, acc[0][3], 0, 0, 0); \
  acc[1][0] = MFMA32(av1, bv0, acc[1][0], 0, 0, 0); \
  acc[1][1] = MFMA32(av1, bv1, acc[1][1], 0, 0, 0); \
  acc[1][2] = MFMA32(av1, bv2, acc[1][2], 0, 0, 0); \
  acc[1][3] = MFMA32(av1, bv3, acc[1][3], 0, 0, 0); \
  __builtin_amdgcn_s_setprio(0); \
} while (0)

__global__ __launch_bounds__(512, 2) void lstm_gemm(const u16* __restrict__ A,
                                                    const u16* __restrict__ Wt,
                                                    const float* __restrict__ c_prev,
                                                    float* __restrict__ out) {
  __shared__ __align__(16) u16 lds[65536];   // 128 KiB
  char* ldsc = (char*)lds;
  const int tid  = threadIdx.x;
  const int lane = tid & 63;
  const int wid  = tid >> 6;
  const int wr   = wid >> 1;   // 0..3: 64-row slice
  const int wcn  = wid & 1;    // 0..1: 128-col slice
  const int la   = lane & 31;
  const int cq   = lane >> 5;

  // XCD-aware swizzle (512 % 8 == 0 -> bijective)
  const int orig = blockIdx.x;
  const int wg   = ((orig & 7) << 6) | (orig >> 3);
  const int bm   = wg & 15;
  const int bn   = wg >> 4;

  const u16* Ab = A  + (size_t)bm * 256 * K_;
  const u16* Bb = Wt + (size_t)bn * 256 * K_;

  // staging: thread -> (row, swizzled 16B chunk) of [256][32] half-tile
  const int grow = tid >> 2;
  const int gch8 = (((tid & 3) ^ ((grow >> 1) & 3)) << 3);
  // fragment reads: logical chunk = ks*2 + cq, XOR (row>>1)&3 (row bits 1..2 = la bits 1..2)
  const int sw  = (la >> 1) & 3;
  const int ck0 = ((cq ^ sw)) << 4;
  const int ck1 = (((2 + cq) ^ sw)) << 4;
  const int aob = (wr * 64 + la) * 64;   // + rt*2048 inside PHASE
  const int bob = (wcn * 128 + la) * 64; // + ct*2048 inside PHASE

  f32x16 acc[2][4] = {};   // [row-tile][col-tile(gate)]

  // ---- c_prev prefetch (oldest in vmcnt queue; drained by prologue VMW) ----
  const int u  = (bn * 2 + wcn) * 32 + la;
  const int rowb = bm * 256 + wr * 64 + 4 * cq;
  float cpv[2][16];
#pragma unroll
  for (int rt = 0; rt < 2; ++rt)
#pragma unroll
    for (int r = 0; r < 16; ++r) {
      int row = rowb + rt * 32 + (r & 3) + 8 * (r >> 2);
      cpv[rt][r] = c_prev[(size_t)row * U_ + u];
    }

  // ---- prologue ----
  STAGE_A(0, 0, 0);
  STAGE_B(0, 0, 0);
  STAGE_A(0, 1, 0);
  STAGE_B(0, 1, 0);
  STAGE_A(1, 0, 1);
  VMW(4);
  __builtin_amdgcn_s_barrier();

  for (int i = 0; i < NIT; ++i) {
    const int t1 = 2 * i + 1;
    const int t2 = 2 * i + 2;
    const int t3 = 2 * i + 3;
    const bool nl = (i + 1 < NIT);
    PHASE(0, 0, 0, { STAGE_B(1, 0, t1); }, {});
    PHASE(0, 0, 1, { STAGE_A(1, 1, t1); }, { VMW(6); });
    PHASE(0, 1, 0, { STAGE_B(1, 1, t1); }, {});
    PHASE(0, 1, 1, { if (nl) STAGE_A(0, 0, t2); },
          { if (nl) { VMW(6); } else { VMW(4); } });
    PHASE(1, 0, 0, { if (nl) STAGE_B(0, 0, t2); }, {});
    PHASE(1, 0, 1, { if (nl) STAGE_A(0, 1, t2); },
          { if (nl) { VMW(6); } else { VMW(0); } });
    PHASE(1, 1, 0, { if (nl) STAGE_B(0, 1, t2); }, {});
    PHASE(1, 1, 1, { if (nl) STAGE_A(1, 0, t3); }, { if (nl) { VMW(6); } });
  }

  // ---- fused LSTM epilogue (C/D: col=lane&31, row=(r&3)+8*(r>>2)+4*cq) ----
  const size_t BU = (size_t)B_ * U_;
#pragma unroll
  for (int rt = 0; rt < 2; ++rt) {
#pragma unroll
    for (int r = 0; r < 16; ++r) {
      int row = rowb + rt * 32 + (r & 3) + 8 * (r >> 2);
      float zi = acc[rt][0][r], zf = acc[rt][1][r];
      float zc = acc[rt][2][r], zo = acc[rt][3][r];
      float iv = hsig(zi), fv = hsig(zf), ov = hsig(zo);
      size_t off = (size_t)row * U_ + u;
      float cv = fv * cpv[rt][r] + iv * ftanh(zc);
      float hv = ov * ftanh(cv);
      out[off]          = hv;
      out[BU + off]     = hv;
      out[2 * BU + off] = cv;
    }
  }
}

extern "C" void kernel_launch(void* const* d_in, const int* in_sizes, int n_in,
                              void* d_out, int out_size, void* d_ws, size_t ws_size,
                              hipStream_t stream) {
  const float* x  = (const float*)d_in[0];
  const float* h  = (const float*)d_in[1];
  const float* cp = (const float*)d_in[2];
  const float* kk = (const float*)d_in[3];
  const float* rk = (const float*)d_in[4];
  float* out = (float*)d_out;

  const size_t bytesA  = (size_t)B_ * K_ * 2;   // 32 MiB
  const size_t bytesWt = (size_t)N_ * K_ * 2;   // 64 MiB
  if (ws_size < bytesA + bytesWt) return;

  u16* Aws = (u16*)d_ws;
  u16* Wt  = (u16*)((char*)d_ws + bytesA);

  cast_a<<<(B_ * K_ / 8) / 256, 256, 0, stream>>>(x, h, Aws);
  cast_wt<<<dim3(64, 64), 256, 0, stream>>>(kk, rk, Wt);
  lstm_gemm<<<dim3(512), dim3(512), 0, stream>>>(Aws, Wt, cp, out);
}